// Round 9
// baseline (151.514 us; speedup 1.0000x reference)
//
#include <hip/hip_runtime.h>
#include <math.h>

// Problem constants
#define NB   4
#define CH   256
#define HW   4096          // 64*64
#define NCOL 216           // 144 offset + 72 mask
#define MTOT 16384         // NB*HW
#define CHW  1048576       // CH*HW
#define EPSV 1e-5f

// ws layout in floats
#define OFF_NHWC 0
#define NHWCSZ   (NB*HW*CH/2)          // bf16 NHWC raw input
#define OFF_OM   (OFF_NHWC + NHWCSZ)   // offmask M x 216 fp32
#define OMSZ     (MTOT*NCOL)
#define OFF_AB   (OFF_OM + OMSZ)       // A bf16 [M][256]
#define ABSZ     (MTOT*CH/2)
#define OFF_WB   (OFF_AB + ABSZ)       // Wc_bt bf16 [256][256]
#define WBSZ     (CH*CH/2)
#define OFF_BI   (OFF_WB + WBSZ)       // bias 256
#define OFF_PT   (OFF_BI + 256)        // partials 4096*2

typedef short bf16x8 __attribute__((ext_vector_type(8)));
typedef float f32x4  __attribute__((ext_vector_type(4)));

__device__ __forceinline__ unsigned short f2bf(float f) {
    unsigned int u = __builtin_bit_cast(unsigned int, f);
    u += 0x7fffu + ((u >> 16) & 1u);           // round-to-nearest-even
    return (unsigned short)(u >> 16);
}

__device__ __forceinline__ float bf2f(unsigned short s) {
    return __builtin_bit_cast(float, (unsigned int)s << 16);
}

// ---- fused: depthwise conv -> bf16 A [m][k] + partials + bf16 NHWC raw x
//      + weight prep (blocks 0..255) + bias (block 0) ----
// grid: 4 n * 8 ctile * 128 hwtile = 4096 blocks; block 256.
__global__ __launch_bounds__(256) void conv_prep_kernel(
    const float* __restrict__ x, const float* __restrict__ dw_w,
    const float* __restrict__ dw_b,
    const float* __restrict__ off_w, const float* __restrict__ off_b,
    const float* __restrict__ mask_w, const float* __restrict__ mask_b,
    unsigned short* __restrict__ A, unsigned short* __restrict__ inp_nhwc,
    unsigned short* __restrict__ Wc_bt, float* __restrict__ bias,
    float* __restrict__ partials) {
    __shared__ float xs[32 * 108];         // [32ch][3row][36col], 34 cols used
    __shared__ unsigned short tb[32 * 36]; // [32pix][36], 32 ch used
    __shared__ float rs1[256], rs2[256];
    int b = blockIdx.x;
    int tid = threadIdx.x;
    // weight prep: block b < 256 handles k=b, all n
    if (b < 256) {
        int k = b, n = tid;
        float v = 0.f;
        if (n < 144)      v = off_w[k * 144 + n];
        else if (n < 216) v = mask_w[k * 72 + (n - 144)];
        Wc_bt[(size_t)n * 256 + k] = f2bf(v);
        if (b == 0) {
            float bb = 0.f;
            if (n < 144)      bb = off_b[n];
            else if (n < 216) bb = mask_b[n - 144];
            bias[n] = bb;
        }
    }
    int ct  = b & 7;
    int hwt = (b >> 3) & 127;
    int n   = b >> 10;
    int c0 = ct * 32;
    int hw0 = hwt * 32;
    int h  = hw0 >> 6;
    int w0 = hw0 & 63;
    const float* xb = x + ((size_t)n * CH + c0) * HW;
    // load 32ch x 3rows x 34cols halo (zero-padded at image border)
    for (int it = 0; it < 13; ++it) {
        int q = it * 256 + tid;
        if (q < 3264) {
            int cl = q / 102;
            int rr = q - cl * 102;
            int r  = rr / 34;
            int i  = rr - r * 34;
            int gh = h - 1 + r;
            int gw = w0 - 1 + i;
            float v = 0.f;
            if (gh >= 0 && gh < 64 && gw >= 0 && gw < 64)
                v = xb[(size_t)cl * HW + gh * 64 + gw];
            xs[cl * 108 + r * 36 + i] = v;
        }
    }
    __syncthreads();
    int wl = tid & 31;            // local pixel
    int cbase = (tid >> 5) * 4;   // 4 channels per thread
    float s1 = 0.f, s2 = 0.f;
    ushort4 o;
    unsigned short ov[4];
#pragma unroll
    for (int j = 0; j < 4; ++j) {
        int c = c0 + cbase + j;
        float acc = dw_b[c];
        const float* wk = dw_w + c * 9;
#pragma unroll
        for (int r = 0; r < 3; ++r)
#pragma unroll
            for (int kx = 0; kx < 3; ++kx)
                acc = fmaf(xs[(cbase + j) * 108 + r * 36 + wl + kx], wk[r * 3 + kx], acc);
        s1 += acc; s2 += acc * acc;
        ov[j] = f2bf(acc);
    }
    o.x = ov[0]; o.y = ov[1]; o.z = ov[2]; o.w = ov[3];
    *(ushort4*)&tb[wl * 36 + cbase] = o;
    rs1[tid] = s1; rs2[tid] = s2;
    // write raw x (center row) as bf16 NHWC, straight from xs
    {
        int r2 = tid >> 3, cg = tid & 7;      // pixel, 4-ch group
        ushort4 rv;
        rv.x = f2bf(xs[(cg * 4 + 0) * 108 + 36 + r2 + 1]);
        rv.y = f2bf(xs[(cg * 4 + 1) * 108 + 36 + r2 + 1]);
        rv.z = f2bf(xs[(cg * 4 + 2) * 108 + 36 + r2 + 1]);
        rv.w = f2bf(xs[(cg * 4 + 3) * 108 + 36 + r2 + 1]);
        *(ushort4*)&inp_nhwc[((size_t)(n * HW + hw0 + r2)) * 256 + c0 + cg * 4] = rv;
    }
    __syncthreads();
    for (int s = 128; s > 0; s >>= 1) {
        if (tid < s) { rs1[tid] += rs1[tid + s]; rs2[tid] += rs2[tid + s]; }
        __syncthreads();
    }
    if (tid == 0) {
        partials[2 * b]     = rs1[0];
        partials[2 * b + 1] = rs2[0];
    }
    // write A bf16 [m][k], 8B per lane, 8 lanes per m-row
    int r2 = tid >> 3, cg = tid & 7;
    ushort4 w4 = *(const ushort4*)&tb[r2 * 36 + cg * 4];
    *(ushort4*)&A[((size_t)(n * HW + hw0 + r2)) * 256 + c0 + cg * 4] = w4;
}

// ---------------- fused norm+gelu bf16 MFMA GEMM (full-N tile) ----------------
// offmask = gelu(norm(A)) @ W + bias.  Tile 32m x 256n, K=256. 512 blocks.
// Stats (mean/rsig) reduced inline from per-block partials.
#define LDK 72
__global__ __launch_bounds__(256) void gemm_fused_kernel(
    const unsigned short* __restrict__ A, const unsigned short* __restrict__ Bt,
    const float* __restrict__ bias, const float* __restrict__ partials,
    const float* __restrict__ gn_g, const float* __restrict__ gn_b,
    float* __restrict__ offmask) {
    __shared__ unsigned short As[32 * LDK];
    __shared__ unsigned short Bs[256 * LDK];
    __shared__ float red1[256], red2[256];
    int m0 = blockIdx.x * 32;
    int n = m0 >> 12;
    int tid = threadIdx.x, lane = tid & 63, wid = tid >> 6;
    // inline stats reduction over this sample's 1024 partial pairs
    float s1 = 0.f, s2 = 0.f;
    for (int i = tid; i < 1024; i += 256) {
        s1 += partials[2 * (n * 1024 + i)];
        s2 += partials[2 * (n * 1024 + i) + 1];
    }
    red1[tid] = s1; red2[tid] = s2;
    __syncthreads();
    for (int st = 128; st > 0; st >>= 1) {
        if (tid < st) { red1[tid] += red1[tid + st]; red2[tid] += red2[tid + st]; }
        __syncthreads();
    }
    float mean = red1[0] * (1.f / (float)CHW);
    float var  = red2[0] * (1.f / (float)CHW) - mean * mean;
    float rsig = rsqrtf(var + EPSV);
    f32x4 acc[2][4] = {};
    for (int k0 = 0; k0 < 256; k0 += 64) {
        // stage A (32x64) with norm+gelu
        {
            int row = tid >> 3, kk0 = (tid & 7) * 8;
            union { uint4 u; unsigned short s[8]; } in, ou;
            in.u = *(const uint4*)&A[((size_t)(m0 + row)) * 256 + k0 + kk0];
#pragma unroll
            for (int j = 0; j < 8; ++j) {
                int ch = k0 + kk0 + j;
                float v = bf2f(in.s[j]);
                v = (v - mean) * rsig * gn_g[ch] + gn_b[ch];
                v = 0.5f * v * (1.0f + erff(v * 0.70710678118654752f));
                ou.s[j] = f2bf(v);
            }
            *(uint4*)&As[row * LDK + kk0] = ou.u;
        }
        // stage B (256x64)
#pragma unroll
        for (int i = 0; i < 8; ++i) {
            int q = i * 256 + tid;
            int mm = q >> 3, kk = (q & 7) * 8;
            *(uint4*)&Bs[mm * LDK + kk] = *(const uint4*)&Bt[(size_t)mm * 256 + k0 + kk];
        }
        __syncthreads();
#pragma unroll
        for (int kh = 0; kh < 2; ++kh) {
            bf16x8 af[2], bfr[4];
#pragma unroll
            for (int mi = 0; mi < 2; ++mi)
                af[mi] = *(const bf16x8*)&As[(mi * 16 + (lane & 15)) * LDK + kh * 32 + (lane >> 4) * 8];
#pragma unroll
            for (int nj = 0; nj < 4; ++nj)
                bfr[nj] = *(const bf16x8*)&Bs[(wid * 64 + nj * 16 + (lane & 15)) * LDK + kh * 32 + (lane >> 4) * 8];
#pragma unroll
            for (int mi = 0; mi < 2; ++mi)
#pragma unroll
                for (int nj = 0; nj < 4; ++nj)
                    acc[mi][nj] = __builtin_amdgcn_mfma_f32_16x16x32_bf16(
                        af[mi], bfr[nj], acc[mi][nj], 0, 0, 0);
        }
        __syncthreads();
    }
#pragma unroll
    for (int nj = 0; nj < 4; ++nj) {
        int col = wid * 64 + nj * 16 + (lane & 15);
        if (col < NCOL) {
            float bcol = bias[col];
#pragma unroll
            for (int mi = 0; mi < 2; ++mi)
#pragma unroll
                for (int r = 0; r < 4; ++r) {
                    int row = m0 + mi * 16 + (lane >> 4) * 4 + r;
                    offmask[(size_t)row * NCOL + col] = acc[mi][nj][r] + bcol;
                }
        }
    }
}

// ---------------- DCNv3 core + NCHW output (bf16 gather input) ----------------
// grid 1024 blocks; block 512 = 8 waves = 16 half-waves; block covers 16
// consecutive pixels (same h row), one half-wave per pixel (32 lanes x 8ch).
// LDS 30.5 KB -> 4 blocks/CU -> 32 waves/CU (2x round-8 occupancy).
__global__ __launch_bounds__(512) void dcn_out_kernel(
    const unsigned short* __restrict__ inp_nhwc, const float* __restrict__ offmask,
    float* __restrict__ out) {
    __shared__ float lom[16 * 216];    // all 16 pixels' offmask rows
    __shared__ float ot[16 * 260];     // [16pix][260], 256 ch used
    int tid = threadIdx.x, lane = tid & 63, wid = tid >> 6;
    int pix0 = blockIdx.x * 16;
    int n = pix0 >> 12;
    int hwb = pix0 & 4095;
    // stage offmask for 16 pixels: 3456 contiguous floats
    for (int i = tid; i < 16 * NCOL; i += 512)
        lom[i] = offmask[(size_t)pix0 * NCOL + i];
    __syncthreads();
    int ph = lane >> 5;            // half-wave
    int l  = lane & 31;            // lane-in-half
    int g  = l >> 2;               // group (4 lanes/group)
    int ch0 = l * 8;               // 8 channels per lane
    const unsigned short* base = inp_nhwc + (size_t)n * HW * 256;
    int pixloc = wid * 2 + ph;     // 0..15
    int hw = hwb + pixloc;
    int h = hw >> 6, w = hw & 63;
    const float* lm = &lom[pixloc * NCOL];
    // softmax over P for this group
    float lg[9];
    float mx = -1e30f;
#pragma unroll
    for (int p = 0; p < 9; ++p) { lg[p] = lm[144 + g * 9 + p]; mx = fmaxf(mx, lg[p]); }
    float sum = 0.f;
#pragma unroll
    for (int p = 0; p < 9; ++p) { lg[p] = __expf(lg[p] - mx); sum += lg[p]; }
    float rs = 1.0f / sum;
    float acc[8] = {};
#pragma unroll
    for (int p = 0; p < 9; ++p) {
        float ox = lm[g * 18 + p * 2];
        float oy = lm[g * 18 + p * 2 + 1];
        // padded coords; pad ring is zeros -> valid iff 1<=idx<=64
        float px = (float)(w + (p / 3)) + ox;
        float py = (float)(h + (p % 3)) + oy;
        float xf = floorf(px), yf = floorf(py);
        float wx = px - xf, wy = py - yf;
        int x0 = (int)xf, y0 = (int)yf;
        float m = lg[p] * rs;
        float w00 = m * (1.f - wy) * (1.f - wx);
        float w01 = m * (1.f - wy) * wx;
        float w10 = m * wy * (1.f - wx);
        float w11 = m * wy * wx;
#pragma unroll
        for (int corner = 0; corner < 4; ++corner) {
            int yi = y0 + (corner >> 1);
            int xi = x0 + (corner & 1);
            float cw = (corner == 0) ? w00 : (corner == 1) ? w01 : (corner == 2) ? w10 : w11;
            bool valid = (yi >= 1) & (yi <= 64) & (xi >= 1) & (xi <= 64);
            int yc = min(max(yi, 1), 64) - 1;
            int xc = min(max(xi, 1), 64) - 1;
            bf16x8 v = *(const bf16x8*)&base[((size_t)yc * 64 + xc) * 256 + ch0];
            float f = valid ? cw : 0.f;
#pragma unroll
            for (int j = 0; j < 8; ++j)
                acc[j] = fmaf(f, bf2f((unsigned short)v[j]), acc[j]);
        }
    }
    *(float4*)&ot[pixloc * 260 + ch0]     = make_float4(acc[0], acc[1], acc[2], acc[3]);
    *(float4*)&ot[pixloc * 260 + ch0 + 4] = make_float4(acc[4], acc[5], acc[6], acc[7]);
    __syncthreads();
    // write NCHW: 16 lanes of consecutive pixels per channel (64B segments)
    int px = tid & 15, crow = tid >> 4;   // crow 0..31
#pragma unroll
    for (int cc = 0; cc < 8; ++cc) {
        int c = cc * 32 + crow;
        out[((size_t)(n * CH + c)) * HW + hwb + px] = ot[px * 260 + c];
    }
}

extern "C" void kernel_launch(void* const* d_in, const int* in_sizes, int n_in,
                              void* d_out, int out_size, void* d_ws, size_t ws_size,
                              hipStream_t stream) {
    const float* x      = (const float*)d_in[0];
    const float* dw_w   = (const float*)d_in[1];
    const float* dw_b   = (const float*)d_in[2];
    const float* gn_g   = (const float*)d_in[3];
    const float* gn_b   = (const float*)d_in[4];
    const float* off_w  = (const float*)d_in[5];
    const float* off_b  = (const float*)d_in[6];
    const float* mask_w = (const float*)d_in[7];
    const float* mask_b = (const float*)d_in[8];
    float* out = (float*)d_out;

    float* ws = (float*)d_ws;
    unsigned short* inp_nhwc = (unsigned short*)(ws + OFF_NHWC);
    float* offmask  = ws + OFF_OM;
    unsigned short* Abf   = (unsigned short*)(ws + OFF_AB);
    unsigned short* Wc_bt = (unsigned short*)(ws + OFF_WB);
    float* bias     = ws + OFF_BI;
    float* partials = ws + OFF_PT;

    conv_prep_kernel<<<4096, 256, 0, stream>>>(x, dw_w, dw_b, off_w, off_b,
                                               mask_w, mask_b, Abf, inp_nhwc,
                                               Wc_bt, bias, partials);
    gemm_fused_kernel<<<512, 256, 0, stream>>>(Abf, Wc_bt, bias, partials,
                                               gn_g, gn_b, offmask);
    dcn_out_kernel<<<1024, 512, 0, stream>>>(inp_nhwc, offmask, out);
}

// Round 10
// 146.411 us; speedup vs baseline: 1.0349x; 1.0349x over previous
//
#include <hip/hip_runtime.h>
#include <math.h>

// Problem constants
#define NB   4
#define CH   256
#define HW   4096          // 64*64
#define NCOL 216           // 144 offset + 72 mask
#define MTOT 16384         // NB*HW
#define CHW  1048576       // CH*HW
#define EPSV 1e-5f

// ws layout in floats
#define OFF_NHWC 0
#define NHWCSZ   (NB*HW*CH/2)          // bf16 NHWC raw input
#define OFF_OM   (OFF_NHWC + NHWCSZ)   // offmask bf16 M x 216
#define OMSZ     (MTOT*NCOL/2)
#define OFF_AB   (OFF_OM + OMSZ)       // A bf16 [M][256]
#define ABSZ     (MTOT*CH/2)
#define OFF_WB   (OFF_AB + ABSZ)       // Wc_bt bf16 [256][256]
#define WBSZ     (CH*CH/2)
#define OFF_BI   (OFF_WB + WBSZ)       // bias 256
#define OFF_PT   (OFF_BI + 256)        // partials 4096*2

typedef short bf16x8 __attribute__((ext_vector_type(8)));
typedef float f32x4  __attribute__((ext_vector_type(4)));

__device__ __forceinline__ unsigned short f2bf(float f) {
    unsigned int u = __builtin_bit_cast(unsigned int, f);
    u += 0x7fffu + ((u >> 16) & 1u);           // round-to-nearest-even
    return (unsigned short)(u >> 16);
}

__device__ __forceinline__ float bf2f(unsigned short s) {
    return __builtin_bit_cast(float, (unsigned int)s << 16);
}

// ---- fused: depthwise conv -> bf16 A [m][k] + partials + bf16 NHWC raw x
//      + weight prep (blocks 0..255) + bias (block 0) ----
// grid: 4 n * 8 ctile * 128 hwtile = 4096 blocks; block 256.
__global__ __launch_bounds__(256) void conv_prep_kernel(
    const float* __restrict__ x, const float* __restrict__ dw_w,
    const float* __restrict__ dw_b,
    const float* __restrict__ off_w, const float* __restrict__ off_b,
    const float* __restrict__ mask_w, const float* __restrict__ mask_b,
    unsigned short* __restrict__ A, unsigned short* __restrict__ inp_nhwc,
    unsigned short* __restrict__ Wc_bt, float* __restrict__ bias,
    float* __restrict__ partials) {
    __shared__ float xs[32 * 108];         // [32ch][3row][36col], 34 cols used
    __shared__ unsigned short tb[32 * 36]; // [32pix][36], 32 ch used
    __shared__ float rs1[256], rs2[256];
    int b = blockIdx.x;
    int tid = threadIdx.x;
    // weight prep: block b < 256 handles k=b, all n
    if (b < 256) {
        int k = b, n = tid;
        float v = 0.f;
        if (n < 144)      v = off_w[k * 144 + n];
        else if (n < 216) v = mask_w[k * 72 + (n - 144)];
        Wc_bt[(size_t)n * 256 + k] = f2bf(v);
        if (b == 0) {
            float bb = 0.f;
            if (n < 144)      bb = off_b[n];
            else if (n < 216) bb = mask_b[n - 144];
            bias[n] = bb;
        }
    }
    int ct  = b & 7;
    int hwt = (b >> 3) & 127;
    int n   = b >> 10;
    int c0 = ct * 32;
    int hw0 = hwt * 32;
    int h  = hw0 >> 6;
    int w0 = hw0 & 63;
    const float* xb = x + ((size_t)n * CH + c0) * HW;
    // load 32ch x 3rows x 34cols halo (zero-padded at image border)
    for (int it = 0; it < 13; ++it) {
        int q = it * 256 + tid;
        if (q < 3264) {
            int cl = q / 102;
            int rr = q - cl * 102;
            int r  = rr / 34;
            int i  = rr - r * 34;
            int gh = h - 1 + r;
            int gw = w0 - 1 + i;
            float v = 0.f;
            if (gh >= 0 && gh < 64 && gw >= 0 && gw < 64)
                v = xb[(size_t)cl * HW + gh * 64 + gw];
            xs[cl * 108 + r * 36 + i] = v;
        }
    }
    __syncthreads();
    int wl = tid & 31;            // local pixel
    int cbase = (tid >> 5) * 4;   // 4 channels per thread
    float s1 = 0.f, s2 = 0.f;
    ushort4 o;
    unsigned short ov[4];
#pragma unroll
    for (int j = 0; j < 4; ++j) {
        int c = c0 + cbase + j;
        float acc = dw_b[c];
        const float* wk = dw_w + c * 9;
#pragma unroll
        for (int r = 0; r < 3; ++r)
#pragma unroll
            for (int kx = 0; kx < 3; ++kx)
                acc = fmaf(xs[(cbase + j) * 108 + r * 36 + wl + kx], wk[r * 3 + kx], acc);
        s1 += acc; s2 += acc * acc;
        ov[j] = f2bf(acc);
    }
    o.x = ov[0]; o.y = ov[1]; o.z = ov[2]; o.w = ov[3];
    *(ushort4*)&tb[wl * 36 + cbase] = o;
    rs1[tid] = s1; rs2[tid] = s2;
    // write raw x (center row) as bf16 NHWC, straight from xs
    {
        int r2 = tid >> 3, cg = tid & 7;      // pixel, 4-ch group
        ushort4 rv;
        rv.x = f2bf(xs[(cg * 4 + 0) * 108 + 36 + r2 + 1]);
        rv.y = f2bf(xs[(cg * 4 + 1) * 108 + 36 + r2 + 1]);
        rv.z = f2bf(xs[(cg * 4 + 2) * 108 + 36 + r2 + 1]);
        rv.w = f2bf(xs[(cg * 4 + 3) * 108 + 36 + r2 + 1]);
        *(ushort4*)&inp_nhwc[((size_t)(n * HW + hw0 + r2)) * 256 + c0 + cg * 4] = rv;
    }
    __syncthreads();
    for (int s = 128; s > 0; s >>= 1) {
        if (tid < s) { rs1[tid] += rs1[tid + s]; rs2[tid] += rs2[tid + s]; }
        __syncthreads();
    }
    if (tid == 0) {
        partials[2 * b]     = rs1[0];
        partials[2 * b + 1] = rs2[0];
    }
    // write A bf16 [m][k], 8B per lane, 8 lanes per m-row
    int r2 = tid >> 3, cg = tid & 7;
    ushort4 w4 = *(const ushort4*)&tb[r2 * 36 + cg * 4];
    *(ushort4*)&A[((size_t)(n * HW + hw0 + r2)) * 256 + c0 + cg * 4] = w4;
}

// ---------------- fused norm+gelu bf16 MFMA GEMM (full-N tile) ----------------
// offmask(bf16) = gelu(norm(A)) @ W + bias.  Tile 32m x 256n, K=256. 512 blocks.
// Stats (mean/rsig) reduced inline from per-block partials.
#define LDK 72
__global__ __launch_bounds__(256) void gemm_fused_kernel(
    const unsigned short* __restrict__ A, const unsigned short* __restrict__ Bt,
    const float* __restrict__ bias, const float* __restrict__ partials,
    const float* __restrict__ gn_g, const float* __restrict__ gn_b,
    unsigned short* __restrict__ offmask) {
    __shared__ unsigned short As[32 * LDK];
    __shared__ unsigned short Bs[256 * LDK];
    __shared__ float red1[256], red2[256];
    int m0 = blockIdx.x * 32;
    int n = m0 >> 12;
    int tid = threadIdx.x, lane = tid & 63, wid = tid >> 6;
    // inline stats reduction over this sample's 1024 partial pairs
    float s1 = 0.f, s2 = 0.f;
    for (int i = tid; i < 1024; i += 256) {
        s1 += partials[2 * (n * 1024 + i)];
        s2 += partials[2 * (n * 1024 + i) + 1];
    }
    red1[tid] = s1; red2[tid] = s2;
    __syncthreads();
    for (int st = 128; st > 0; st >>= 1) {
        if (tid < st) { red1[tid] += red1[tid + st]; red2[tid] += red2[tid + st]; }
        __syncthreads();
    }
    float mean = red1[0] * (1.f / (float)CHW);
    float var  = red2[0] * (1.f / (float)CHW) - mean * mean;
    float rsig = rsqrtf(var + EPSV);
    f32x4 acc[2][4] = {};
    for (int k0 = 0; k0 < 256; k0 += 64) {
        // stage A (32x64) with norm+gelu
        {
            int row = tid >> 3, kk0 = (tid & 7) * 8;
            union { uint4 u; unsigned short s[8]; } in, ou;
            in.u = *(const uint4*)&A[((size_t)(m0 + row)) * 256 + k0 + kk0];
#pragma unroll
            for (int j = 0; j < 8; ++j) {
                int ch = k0 + kk0 + j;
                float v = bf2f(in.s[j]);
                v = (v - mean) * rsig * gn_g[ch] + gn_b[ch];
                v = 0.5f * v * (1.0f + erff(v * 0.70710678118654752f));
                ou.s[j] = f2bf(v);
            }
            *(uint4*)&As[row * LDK + kk0] = ou.u;
        }
        // stage B (256x64)
#pragma unroll
        for (int i = 0; i < 8; ++i) {
            int q = i * 256 + tid;
            int mm = q >> 3, kk = (q & 7) * 8;
            *(uint4*)&Bs[mm * LDK + kk] = *(const uint4*)&Bt[(size_t)mm * 256 + k0 + kk];
        }
        __syncthreads();
#pragma unroll
        for (int kh = 0; kh < 2; ++kh) {
            bf16x8 af[2], bfr[4];
#pragma unroll
            for (int mi = 0; mi < 2; ++mi)
                af[mi] = *(const bf16x8*)&As[(mi * 16 + (lane & 15)) * LDK + kh * 32 + (lane >> 4) * 8];
#pragma unroll
            for (int nj = 0; nj < 4; ++nj)
                bfr[nj] = *(const bf16x8*)&Bs[(wid * 64 + nj * 16 + (lane & 15)) * LDK + kh * 32 + (lane >> 4) * 8];
#pragma unroll
            for (int mi = 0; mi < 2; ++mi)
#pragma unroll
                for (int nj = 0; nj < 4; ++nj)
                    acc[mi][nj] = __builtin_amdgcn_mfma_f32_16x16x32_bf16(
                        af[mi], bfr[nj], acc[mi][nj], 0, 0, 0);
        }
        __syncthreads();
    }
#pragma unroll
    for (int nj = 0; nj < 4; ++nj) {
        int col = wid * 64 + nj * 16 + (lane & 15);
        if (col < NCOL) {
            float bcol = bias[col];
#pragma unroll
            for (int mi = 0; mi < 2; ++mi)
#pragma unroll
                for (int r = 0; r < 4; ++r) {
                    int row = m0 + mi * 16 + (lane >> 4) * 4 + r;
                    offmask[(size_t)row * NCOL + col] = f2bf(acc[mi][nj][r] + bcol);
                }
        }
    }
}

// ---------------- DCNv3 core + NCHW output (bf16 gather + bf16 offmask) ----------------
// grid 1024 blocks; block 256 = 4 waves; block covers 16 consecutive pixels
// (same h row). Each half-wave (32 lanes x 8ch) owns one pixel; wave = 2 pixels,
// 2 iterations. Output staged in LDS, written NCHW directly.  (R8 config.)
__global__ __launch_bounds__(256) void dcn_out_kernel(
    const unsigned short* __restrict__ inp_nhwc, const unsigned short* __restrict__ offmask,
    float* __restrict__ out) {
    __shared__ float lom[16 * 216];    // all 16 pixels' offmask rows (fp32 in LDS)
    __shared__ float ot[16 * 260];     // [16pix][260], 256 ch used
    int tid = threadIdx.x, lane = tid & 63, wid = tid >> 6;
    int pix0 = blockIdx.x * 16;
    int n = pix0 >> 12;
    int hwb = pix0 & 4095;
    // stage offmask for 16 pixels: 3456 bf16 = 1728 uints, convert to fp32
    {
        const unsigned int* om2 = (const unsigned int*)(offmask + (size_t)pix0 * NCOL);
        for (int i = tid; i < 16 * NCOL / 2; i += 256) {
            unsigned int v = om2[i];
            lom[2 * i]     = bf2f((unsigned short)(v & 0xffffu));
            lom[2 * i + 1] = bf2f((unsigned short)(v >> 16));
        }
    }
    __syncthreads();
    int ph = lane >> 5;            // half-wave
    int l  = lane & 31;            // lane-in-half
    int g  = l >> 2;               // group (4 lanes/group)
    int ch0 = l * 8;               // 8 channels per lane
    const unsigned short* base = inp_nhwc + (size_t)n * HW * 256;
#pragma unroll
    for (int it = 0; it < 2; ++it) {
        int pixloc = it * 8 + wid * 2 + ph;
        int hw = hwb + pixloc;
        int h = hw >> 6, w = hw & 63;
        const float* lm = &lom[pixloc * NCOL];
        // softmax over P for this group
        float lg[9];
        float mx = -1e30f;
#pragma unroll
        for (int p = 0; p < 9; ++p) { lg[p] = lm[144 + g * 9 + p]; mx = fmaxf(mx, lg[p]); }
        float sum = 0.f;
#pragma unroll
        for (int p = 0; p < 9; ++p) { lg[p] = __expf(lg[p] - mx); sum += lg[p]; }
        float rs = 1.0f / sum;
        float acc[8] = {};
#pragma unroll
        for (int p = 0; p < 9; ++p) {
            float ox = lm[g * 18 + p * 2];
            float oy = lm[g * 18 + p * 2 + 1];
            // padded coords; pad ring is zeros -> valid iff 1<=idx<=64
            float px = (float)(w + (p / 3)) + ox;
            float py = (float)(h + (p % 3)) + oy;
            float xf = floorf(px), yf = floorf(py);
            float wx = px - xf, wy = py - yf;
            int x0 = (int)xf, y0 = (int)yf;
            float m = lg[p] * rs;
            float w00 = m * (1.f - wy) * (1.f - wx);
            float w01 = m * (1.f - wy) * wx;
            float w10 = m * wy * (1.f - wx);
            float w11 = m * wy * wx;
#pragma unroll
            for (int corner = 0; corner < 4; ++corner) {
                int yi = y0 + (corner >> 1);
                int xi = x0 + (corner & 1);
                float cw = (corner == 0) ? w00 : (corner == 1) ? w01 : (corner == 2) ? w10 : w11;
                bool valid = (yi >= 1) & (yi <= 64) & (xi >= 1) & (xi <= 64);
                int yc = min(max(yi, 1), 64) - 1;
                int xc = min(max(xi, 1), 64) - 1;
                bf16x8 v = *(const bf16x8*)&base[((size_t)yc * 64 + xc) * 256 + ch0];
                float f = valid ? cw : 0.f;
#pragma unroll
                for (int j = 0; j < 8; ++j)
                    acc[j] = fmaf(f, bf2f((unsigned short)v[j]), acc[j]);
            }
        }
        *(float4*)&ot[pixloc * 260 + ch0]     = make_float4(acc[0], acc[1], acc[2], acc[3]);
        *(float4*)&ot[pixloc * 260 + ch0 + 4] = make_float4(acc[4], acc[5], acc[6], acc[7]);
    }
    __syncthreads();
    // write NCHW: 16 lanes of consecutive pixels per channel (64B segments)
    int px = tid & 15, crow = tid >> 4;   // crow 0..15
#pragma unroll
    for (int cc = 0; cc < 16; ++cc) {
        int c = cc * 16 + crow;
        out[((size_t)(n * CH + c)) * HW + hwb + px] = ot[px * 260 + c];
    }
}

extern "C" void kernel_launch(void* const* d_in, const int* in_sizes, int n_in,
                              void* d_out, int out_size, void* d_ws, size_t ws_size,
                              hipStream_t stream) {
    const float* x      = (const float*)d_in[0];
    const float* dw_w   = (const float*)d_in[1];
    const float* dw_b   = (const float*)d_in[2];
    const float* gn_g   = (const float*)d_in[3];
    const float* gn_b   = (const float*)d_in[4];
    const float* off_w  = (const float*)d_in[5];
    const float* off_b  = (const float*)d_in[6];
    const float* mask_w = (const float*)d_in[7];
    const float* mask_b = (const float*)d_in[8];
    float* out = (float*)d_out;

    float* ws = (float*)d_ws;
    unsigned short* inp_nhwc = (unsigned short*)(ws + OFF_NHWC);
    unsigned short* offmask  = (unsigned short*)(ws + OFF_OM);
    unsigned short* Abf   = (unsigned short*)(ws + OFF_AB);
    unsigned short* Wc_bt = (unsigned short*)(ws + OFF_WB);
    float* bias     = ws + OFF_BI;
    float* partials = ws + OFF_PT;

    conv_prep_kernel<<<4096, 256, 0, stream>>>(x, dw_w, dw_b, off_w, off_b,
                                               mask_w, mask_b, Abf, inp_nhwc,
                                               Wc_bt, bias, partials);
    gemm_fused_kernel<<<512, 256, 0, stream>>>(Abf, Wc_bt, bias, partials,
                                               gn_g, gn_b, offmask);
    dcn_out_kernel<<<1024, 256, 0, stream>>>(inp_nhwc, offmask, out);
}